// Round 15
// baseline (978.989 us; speedup 1.0000x reference)
//
#include <hip/hip_runtime.h>
#include <hip/hip_cooperative_groups.h>
#include <cmath>

namespace cg = cooperative_groups;

typedef __attribute__((ext_vector_type(2))) float v2f;

__device__ __forceinline__ float lo16(unsigned u){ union{unsigned x; float f;} c; c.x = u << 16; return c.f; }
__device__ __forceinline__ float hi16(unsigned u){ union{unsigned x; float f;} c; c.x = u & 0xffff0000u; return c.f; }
__device__ __forceinline__ v2f pkmax(v2f a, v2f b){ v2f r; r.x = fmaxf(a.x,b.x); r.y = fmaxf(a.y,b.y); return r; }
__device__ __forceinline__ v2f mkv2(unsigned u){ v2f r; r.x = lo16(u); r.y = hi16(u); return r; }
__device__ __forceinline__ unsigned short f2bf(float f){
  union { float f; unsigned u; } c; c.f = f;
  unsigned u = c.u + 0x7FFFu + ((c.u >> 16) & 1u);
  return (unsigned short)(u >> 16);
}
__device__ __forceinline__ unsigned pack2bf(float a, float b){
  return (unsigned)f2bf(a) | ((unsigned)f2bf(b) << 16);
}
// safe merge factor: exp(m-M), giving 1 when m==M (handles -inf==-inf)
__device__ __forceinline__ float mergef(float m, float M){ return (m == M) ? 1.f : __expf(m - M); }

#define LOG2E 1.4426950408889634f

typedef __attribute__((ext_vector_type(8))) short bfrag;   // 8 bf16 = 4 VGPR
typedef __attribute__((ext_vector_type(4))) float ffrag;   // 4 f32 acc

// ---------------- cooperative CSR build + precision prep (single launch) ----------------
// phases: [zero degi | prep Xbf/WT1/WT2] -> deg -> block-sums -> scan -> rescan(+cur) -> scatter

#define CSR_GRID 1024

__global__ __launch_bounds__(256) void csr_prep_kernel(
    const int* __restrict__ src, const int* __restrict__ dst,
    int* __restrict__ degi, int* __restrict__ bsum, int* __restrict__ boff,
    int* __restrict__ row_off, int* __restrict__ cur, int* __restrict__ csr_src,
    const float* __restrict__ x,
    const float* __restrict__ W1l, const float* __restrict__ W1r,
    const float* __restrict__ W2l, const float* __restrict__ W2r,
    unsigned short* __restrict__ Xbf, unsigned short* __restrict__ WT1,
    unsigned short* __restrict__ WT2,
    int N, int E, int NB)
{
  cg::grid_group grid = cg::this_grid();
  __shared__ int s[256];
  int t = threadIdx.x;
  int gtid = blockIdx.x*256 + t;
  int gsize = gridDim.x*256;

  // phase 0: zero degi + precision prep (independent)
  for (int i = gtid; i < N; i += gsize) degi[i] = 0;
  {
    int n1 = N*160;              // x [N,129] -> Xbf [N,160]
    int n2 = 2*256*160;          // WT1 [512,160]
    int n3 = 2*128*256;          // WT2 [256,256]
    int total = n1 + n2 + n3;
    for (int idx = gtid; idx < total; idx += gsize){
      if (idx < n1){
        int n = idx / 160, k = idx - n*160;
        Xbf[idx] = (k < 129) ? f2bf(x[(size_t)n*129 + k]) : (unsigned short)0;
      } else if (idx < n1 + n2){
        int j = idx - n1;
        int c = j / 160, k = j - c*160;
        float v = 0.f;
        if (k < 129) v = (c < 256) ? W1l[(size_t)k*256 + c] : W1r[(size_t)k*256 + (c - 256)];
        WT1[j] = f2bf(v);
      } else {
        int j = idx - n1 - n2;
        int c = j >> 8, k = j & 255;
        float v = (c < 128) ? W2l[(size_t)k*128 + c] : W2r[(size_t)k*128 + (c - 128)];
        WT2[j] = f2bf(v);
      }
    }
  }
  grid.sync();

  // phase 1: degree count
  for (int e = gtid; e < E; e += gsize) atomicAdd(&degi[dst[e]], 1);
  grid.sync();

  // phase 2: per-chunk block sums
  for (int chunk = blockIdx.x; chunk < NB; chunk += gridDim.x){
    int i = chunk*256 + t;
    s[t] = (i < N) ? degi[i] : 0;
    __syncthreads();
    for (int off = 128; off > 0; off >>= 1){
      if (t < off) s[t] += s[t + off];
      __syncthreads();
    }
    if (t == 0) bsum[chunk] = s[0];
    __syncthreads();
  }
  grid.sync();

  // phase 3: scan of block sums (single block; NB <= 256)
  if (blockIdx.x == 0){
    int v = (t < NB) ? bsum[t] : 0;
    s[t] = v;
    __syncthreads();
    for (int off = 1; off < 256; off <<= 1){
      int q = (t >= off) ? s[t - off] : 0;
      __syncthreads();
      s[t] += q;
      __syncthreads();
    }
    if (t < NB) boff[t] = s[t] - v;
    if (t == NB-1) row_off[N] = s[t];
  }
  grid.sync();

  // phase 4: per-chunk rescan -> row_off and cur
  for (int chunk = blockIdx.x; chunk < NB; chunk += gridDim.x){
    int i = chunk*256 + t;
    int v = (i < N) ? degi[i] : 0;
    s[t] = v;
    __syncthreads();
    for (int off = 1; off < 256; off <<= 1){
      int q = (t >= off) ? s[t - off] : 0;
      __syncthreads();
      s[t] += q;
      __syncthreads();
    }
    if (i < N){
      int ro = boff[chunk] + s[t] - v;
      row_off[i] = ro;
      cur[i] = ro;
    }
    __syncthreads();
  }
  grid.sync();

  // phase 5: scatter
  for (int e = gtid; e < E; e += gsize){
    int pos = atomicAdd(&cur[dst[e]], 1);
    csr_src[pos] = src[e];
  }
}

// ---------------- dual MFMA bf16 GEMM, CB col-tiles of 128 per block ----------------

template<int CB>
__global__ __launch_bounds__(256) void gemm_dual(const unsigned short* __restrict__ Xbf,
                                                 const unsigned short* __restrict__ WT,
                                                 unsigned short* __restrict__ outL,
                                                 unsigned short* __restrict__ outR,
                                                 int N, int Kpad, int Mhalf){
  __shared__ __attribute__((aligned(16))) unsigned short Xs[128*40];
  __shared__ __attribute__((aligned(16))) unsigned short Ws[CB*128*40];
  int t = threadIdx.x;
  int n0 = blockIdx.x*128, c0 = blockIdx.y*(CB*128);
  int wv = t >> 6, lane = t & 63;
  int wr = wv >> 1, wc = wv & 1;
  int m16 = lane & 15, quad = lane >> 4;

  ffrag acc[CB][4][4];
  #pragma unroll
  for (int cb = 0; cb < CB; cb++)
    #pragma unroll
    for (int i = 0; i < 4; i++)
      #pragma unroll
      for (int j = 0; j < 4; j++) acc[cb][i][j] = (ffrag){0.f,0.f,0.f,0.f};

  for (int k0 = 0; k0 < Kpad; k0 += 32){
    uint4 zero = {0,0,0,0};
    #pragma unroll
    for (int it = 0; it < 2; it++){
      int idx = t + it*256;
      int r = idx >> 2, g = idx & 3;
      int n = n0 + r;
      uint4 v = (n < N) ? *(const uint4*)&Xbf[(size_t)n*Kpad + k0 + g*8] : zero;
      *(uint4*)&Xs[r*40 + g*8] = v;
    }
    #pragma unroll
    for (int it = 0; it < 2*CB; it++){
      int idx = t + it*256;
      int c = idx >> 2, g = idx & 3;
      uint4 v = *(const uint4*)&WT[(size_t)(c0 + c)*Kpad + k0 + g*8];
      *(uint4*)&Ws[c*40 + g*8] = v;
    }
    __syncthreads();
    bfrag a[4];
    #pragma unroll
    for (int i = 0; i < 4; i++)
      a[i] = *(const bfrag*)&Xs[(wr*64 + i*16 + m16)*40 + quad*8];
    #pragma unroll
    for (int cb = 0; cb < CB; cb++){
      bfrag b[4];
      #pragma unroll
      for (int j = 0; j < 4; j++)
        b[j] = *(const bfrag*)&Ws[(cb*128 + wc*64 + j*16 + m16)*40 + quad*8];
      #pragma unroll
      for (int i = 0; i < 4; i++)
        #pragma unroll
        for (int j = 0; j < 4; j++)
          acc[cb][i][j] = __builtin_amdgcn_mfma_f32_16x16x32_bf16(a[i], b[j], acc[cb][i][j], 0, 0, 0);
    }
    __syncthreads();
  }

  #pragma unroll
  for (int cb = 0; cb < CB; cb++){
    int gc0 = c0 + cb*128;
    bool isL = (gc0 < Mhalf);
    unsigned short* outp = isL ? outL : outR;
    int ccol0 = isL ? gc0 : (gc0 - Mhalf);
    #pragma unroll
    for (int i = 0; i < 4; i++){
      #pragma unroll
      for (int reg = 0; reg < 4; reg++){
        int rr = n0 + wr*64 + i*16 + quad*4 + reg;
        if (rr >= N) continue;
        #pragma unroll
        for (int j = 0; j < 4; j++){
          int cc = ccol0 + wc*64 + j*16 + m16;
          outp[(size_t)rr*Mhalf + cc] = f2bf(acc[cb][i][j][reg]);
        }
      }
    }
  }
}

// ---------------- fused GATv2 edge phase (packed-f32 channel math) ----------------
// H=2, CH=256: wave per node, 2 edge slots x 32 lanes (16/head), 8 ch/lane. bf16 in/out.

__global__ __launch_bounds__(256) void fused_gat_wave2(
    const int* __restrict__ row_off, const int* __restrict__ csr_src,
    const unsigned short* __restrict__ xlbf, const unsigned short* __restrict__ xrbf,
    const float* __restrict__ att, const float* __restrict__ bias,
    unsigned short* __restrict__ outbf, int N)
{
  int n = blockIdx.x*4 + (threadIdx.x >> 6);
  if (n >= N) return;
  int lane = threadIdx.x & 63;
  int slot = lane >> 5;
  int sub  = lane & 31;
  int ch0  = sub*8;
  int r0 = row_off[n], r1 = row_off[n+1];
  int deg = r1 - r0;

  uint4 xru = *(const uint4*)&xrbf[(size_t)n*256 + ch0];
  v2f q01 = mkv2(xru.x), q23 = mkv2(xru.y), q45 = mkv2(xru.z), q67 = mkv2(xru.w);
  const v2f* atp = (const v2f*)(att + ch0);
  v2f at01 = atp[0], at23 = atp[1], at45 = atp[2], at67 = atp[3];

  float m = -INFINITY, l = 0.f;
  v2f A01 = {0.f,0.f}, A23 = {0.f,0.f}, A45 = {0.f,0.f}, A67 = {0.f,0.f};

  if (deg > 0){
    int p = r0 + slot;
    int pc = min(p, r1-1);
    uint4 cur = *(const uint4*)&xlbf[(size_t)csr_src[pc]*256 + ch0];
    for (; p < r1; p += 2){
      int pn = min(p+2, r1-1);
      uint4 nxt = *(const uint4*)&xlbf[(size_t)csr_src[pn]*256 + ch0];
      v2f x01 = mkv2(cur.x), x23 = mkv2(cur.y), x45 = mkv2(cur.z), x67 = mkv2(cur.w);
      v2f t01 = x01 + q01, t23 = x23 + q23, t45 = x45 + q45, t67 = x67 + q67;
      v2f dv = pkmax(t01, t01*0.2f)*at01;
      dv += pkmax(t23, t23*0.2f)*at23;
      dv += pkmax(t45, t45*0.2f)*at45;
      dv += pkmax(t67, t67*0.2f)*at67;
      float dot = dv.x + dv.y;
      dot += __shfl_xor(dot, 8);
      dot += __shfl_xor(dot, 4);
      dot += __shfl_xor(dot, 2);
      dot += __shfl_xor(dot, 1);   // per-16-lane (head) logit
      if (dot <= m){
        float w_ = __expf(dot - m);
        l += w_;
        A01 += x01*w_; A23 += x23*w_; A45 += x45*w_; A67 += x67*w_;
      } else {
        float sc = __expf(m - dot);   // 0 on first edge (m=-inf)
        l = l*sc + 1.f;
        A01 = A01*sc + x01; A23 = A23*sc + x23; A45 = A45*sc + x45; A67 = A67*sc + x67;
        m = dot;
      }
      cur = nxt;
    }
  }

  const float4* bvp = (const float4*)(bias + ch0);
  float4 res0 = bvp[0], res1 = bvp[1];
  if (deg > 0){
    float m2 = __shfl_xor(m, 32);
    float l2 = __shfl_xor(l, 32);
    float M  = fmaxf(m, m2);
    float fa = mergef(m, M), fb = mergef(m2, M);
    float L  = l*fa + l2*fb;
    v2f q;
    q.x = __shfl_xor(A01.x,32); q.y = __shfl_xor(A01.y,32); A01 = A01*fa + q*fb;
    q.x = __shfl_xor(A23.x,32); q.y = __shfl_xor(A23.y,32); A23 = A23*fa + q*fb;
    q.x = __shfl_xor(A45.x,32); q.y = __shfl_xor(A45.y,32); A45 = A45*fa + q*fb;
    q.x = __shfl_xor(A67.x,32); q.y = __shfl_xor(A67.y,32); A67 = A67*fa + q*fb;
    float inv = 1.f / (L * (float)deg);
    res0.x += A01.x*inv; res0.y += A01.y*inv; res0.z += A23.x*inv; res0.w += A23.y*inv;
    res1.x += A45.x*inv; res1.y += A45.y*inv; res1.z += A67.x*inv; res1.w += A67.y*inv;
  }
  if (slot == 0){
    uint4 u;
    u.x = pack2bf(res0.x, res0.y);
    u.y = pack2bf(res0.z, res0.w);
    u.z = pack2bf(res1.x, res1.y);
    u.w = pack2bf(res1.z, res1.w);
    *(uint4*)&outbf[(size_t)n*256 + ch0] = u;
  }
}

// H=1, CH=128: wave per node, 4 edge slots x 16 lanes, 8 ch/lane.
// Epilogue fuses layer-3 projection (h2 never stored).

__global__ __launch_bounds__(256) void fused_gat_wave1(
    const int* __restrict__ row_off, const int* __restrict__ csr_src,
    const unsigned short* __restrict__ xlbf, const unsigned short* __restrict__ xrbf,
    const float* __restrict__ att, const float* __restrict__ bias,
    const float* __restrict__ W3l, const float* __restrict__ W3r,
    float* __restrict__ xl3, float* __restrict__ xr3, int N)
{
  int n = blockIdx.x*4 + (threadIdx.x >> 6);
  if (n >= N) return;
  int lane = threadIdx.x & 63;
  int slot = lane >> 4;
  int sub  = lane & 15;
  int ch0  = sub*8;
  int r0 = row_off[n], r1 = row_off[n+1];
  int deg = r1 - r0;

  uint4 xru = *(const uint4*)&xrbf[(size_t)n*128 + ch0];
  v2f q01 = mkv2(xru.x), q23 = mkv2(xru.y), q45 = mkv2(xru.z), q67 = mkv2(xru.w);
  const v2f* atp = (const v2f*)(att + ch0);
  v2f at01 = atp[0], at23 = atp[1], at45 = atp[2], at67 = atp[3];

  float m = -INFINITY, l = 0.f;
  v2f A01 = {0.f,0.f}, A23 = {0.f,0.f}, A45 = {0.f,0.f}, A67 = {0.f,0.f};

  if (deg > 0){
    int p = r0 + slot;
    int pc = min(p, r1-1);
    uint4 cur = *(const uint4*)&xlbf[(size_t)csr_src[pc]*128 + ch0];
    for (; p < r1; p += 4){
      int pn = min(p+4, r1-1);
      uint4 nxt = *(const uint4*)&xlbf[(size_t)csr_src[pn]*128 + ch0];
      v2f x01 = mkv2(cur.x), x23 = mkv2(cur.y), x45 = mkv2(cur.z), x67 = mkv2(cur.w);
      v2f t01 = x01 + q01, t23 = x23 + q23, t45 = x45 + q45, t67 = x67 + q67;
      v2f dv = pkmax(t01, t01*0.2f)*at01;
      dv += pkmax(t23, t23*0.2f)*at23;
      dv += pkmax(t45, t45*0.2f)*at45;
      dv += pkmax(t67, t67*0.2f)*at67;
      float dot = dv.x + dv.y;
      dot += __shfl_xor(dot, 8);
      dot += __shfl_xor(dot, 4);
      dot += __shfl_xor(dot, 2);
      dot += __shfl_xor(dot, 1);   // per-16-lane logit
      if (dot <= m){
        float w_ = __expf(dot - m);
        l += w_;
        A01 += x01*w_; A23 += x23*w_; A45 += x45*w_; A67 += x67*w_;
      } else {
        float sc = __expf(m - dot);
        l = l*sc + 1.f;
        A01 = A01*sc + x01; A23 = A23*sc + x23; A45 = A45*sc + x45; A67 = A67*sc + x67;
        m = dot;
      }
      cur = nxt;
    }
  }

  if (deg > 0){
    #pragma unroll
    for (int stage = 0; stage < 2; stage++){
      int d = 16 << stage;
      float m2 = __shfl_xor(m, d);
      float l2 = __shfl_xor(l, d);
      float M  = fmaxf(m, m2);
      float fa = mergef(m, M), fb = mergef(m2, M);
      l = l*fa + l2*fb;
      v2f q;
      q.x = __shfl_xor(A01.x,d); q.y = __shfl_xor(A01.y,d); A01 = A01*fa + q*fb;
      q.x = __shfl_xor(A23.x,d); q.y = __shfl_xor(A23.y,d); A23 = A23*fa + q*fb;
      q.x = __shfl_xor(A45.x,d); q.y = __shfl_xor(A45.y,d); A45 = A45*fa + q*fb;
      q.x = __shfl_xor(A67.x,d); q.y = __shfl_xor(A67.y,d); A67 = A67*fa + q*fb;
      m = M;
    }
  }
  float inv = (deg > 0) ? 1.f/(l*(float)deg) : 0.f;
  const float4* bvp = (const float4*)(bias + ch0);
  float4 res0 = bvp[0], res1 = bvp[1];
  res0.x += A01.x*inv; res0.y += A01.y*inv; res0.z += A23.x*inv; res0.w += A23.y*inv;
  res1.x += A45.x*inv; res1.y += A45.y*inv; res1.z += A67.x*inv; res1.w += A67.y*inv;

  // layer-3 projection in-register: h2 row = res; dot with W3l/W3r
  float4 wla = *(const float4*)(W3l + ch0);
  float4 wlb = *(const float4*)(W3l + ch0 + 4);
  float4 wra = *(const float4*)(W3r + ch0);
  float4 wrb = *(const float4*)(W3r + ch0 + 4);
  float sl = res0.x*wla.x + res0.y*wla.y + res0.z*wla.z + res0.w*wla.w
           + res1.x*wlb.x + res1.y*wlb.y + res1.z*wlb.z + res1.w*wlb.w;
  float sr = res0.x*wra.x + res0.y*wra.y + res0.z*wra.z + res0.w*wra.w
           + res1.x*wrb.x + res1.y*wrb.y + res1.z*wrb.z + res1.w*wrb.w;
  sl += __shfl_xor(sl, 8); sl += __shfl_xor(sl, 4); sl += __shfl_xor(sl, 2); sl += __shfl_xor(sl, 1);
  sr += __shfl_xor(sr, 8); sr += __shfl_xor(sr, 4); sr += __shfl_xor(sr, 2); sr += __shfl_xor(sr, 1);
  if (lane == 0){ xl3[n] = sl; xr3[n] = sr; }
}

// ---------------- layer 3 aggregation + output, per train index (exp2 domain) ----------------

__global__ __launch_bounds__(256) void aggr3out_wave(
    const int* __restrict__ row_off, const int* __restrict__ csr_src,
    const float* __restrict__ xl3, const float* __restrict__ xr3,
    const float* __restrict__ a3, const float* __restrict__ b3,
    const float* __restrict__ y, const int* __restrict__ tidx,
    float* __restrict__ out, int T)
{
  int i = blockIdx.x*4 + (threadIdx.x >> 6);
  if (i >= T) return;
  int lane = threadIdx.x & 63;
  int n = tidx[i];
  int r0 = row_off[n], r1 = row_off[n+1];
  int deg = r1 - r0;
  float b = b3[0];
  float h;
  if (deg == 0){
    h = b;
  } else {
    float xrv = xr3[n];
    float aa = a3[0] * LOG2E;
    float m = -INFINITY, den = 0.f, s = 0.f;
    for (int base = r0; base < r1; base += 64){
      int p = base + lane;
      bool valid = p < r1;
      float xlv = valid ? xl3[csr_src[p]] : 0.f;
      float t = xlv + xrv;
      float v = fmaxf(t, 0.2f*t) * aa;
      if (!valid) v = -INFINITY;
      float bm = v;
      #pragma unroll
      for (int off = 32; off > 0; off >>= 1) bm = fmaxf(bm, __shfl_xor(bm, off));
      float nm = fmaxf(m, bm);
      float a = valid ? exp2f(v - nm) : 0.f;
      float bd = a, bs = a * xlv;
      #pragma unroll
      for (int off = 32; off > 0; off >>= 1){
        bd += __shfl_xor(bd, off);
        bs += __shfl_xor(bs, off);
      }
      float sc = exp2f(m - nm);
      den = den*sc + bd;
      s   = s*sc + bs;
      m = nm;
    }
    h = s/den/(float)deg + b;
  }
  if (lane == 0){
    out[i] = 1.f/(1.f + __expf(-h));
    out[T + i] = y[n];
  }
}

// ---------------- launch ----------------

extern "C" void kernel_launch(void* const* d_in, const int* in_sizes, int n_in,
                              void* d_out, int out_size, void* d_ws, size_t ws_size,
                              hipStream_t stream){
  const float* x    = (const float*)d_in[0];
  const int*   ei   = (const int*)d_in[1];
  const float* y    = (const float*)d_in[2];
  const int*   tidx = (const int*)d_in[3];
  const float* W1l  = (const float*)d_in[4];
  const float* W1r  = (const float*)d_in[5];
  const float* a1   = (const float*)d_in[6];
  const float* b1   = (const float*)d_in[7];
  const float* W2l  = (const float*)d_in[8];
  const float* W2r  = (const float*)d_in[9];
  const float* a2   = (const float*)d_in[10];
  const float* b2   = (const float*)d_in[11];
  const float* W3l  = (const float*)d_in[12];
  const float* W3r  = (const float*)d_in[13];
  const float* a3   = (const float*)d_in[14];
  const float* b3   = (const float*)d_in[15];

  int N = in_sizes[2];        // 50000 nodes
  int E = in_sizes[1] / 2;    // 800000 edges
  int T = in_sizes[3];        // 40000 train indices
  const int* src = ei;
  const int* dst = ei + E;
  int NB = (N + 255) / 256;

  char* w = (char*)d_ws;
  size_t off = 0;
  auto take = [&](size_t bytes) -> char* {
    char* p = w + off;
    off = (off + bytes + 255) & ~(size_t)255;
    return p;
  };
  int*   row_off = (int*)  take((size_t)(N+1)*4);
  int*   degi    = (int*)  take((size_t)N*4);
  int*   cur     = (int*)  take((size_t)N*4);
  int*   bsum    = (int*)  take((size_t)NB*4);
  int*   boff    = (int*)  take((size_t)NB*4);
  int*   csr_src = (int*)  take((size_t)E*4);
  unsigned short* WT1 = (unsigned short*)take((size_t)512*160*2);
  unsigned short* WT2 = (unsigned short*)take((size_t)256*256*2);
  float* A       = (float*)take((size_t)N*256*4);
  float* B       = (float*)take((size_t)N*256*4);

  // ---- buffer map (floats units) ----
  unsigned short* xl1bf = (unsigned short*)A;                   // A lower: N*256 bf16
  unsigned short* Xbf   = (unsigned short*)(A + (size_t)N*128); // A upper: N*160 bf16
  unsigned short* h1bf  = (unsigned short*)(A + (size_t)N*128); // A upper after gemm1 (Xbf dead)
  unsigned short* xr1bf = (unsigned short*)B;                   // B lower: N*256 bf16
  float* Bu   = B + (size_t)N*128;                              // B upper
  float* xl3  = Bu;
  float* xr3  = Bu + N;

  // ---- CSR build + prep: single cooperative launch ----
  {
    void* args[] = {
      (void*)&src, (void*)&dst, (void*)&degi, (void*)&bsum, (void*)&boff,
      (void*)&row_off, (void*)&cur, (void*)&csr_src,
      (void*)&x, (void*)&W1l, (void*)&W1r, (void*)&W2l, (void*)&W2r,
      (void*)&Xbf, (void*)&WT1, (void*)&WT2,
      (void*)&N, (void*)&E, (void*)&NB
    };
    hipLaunchCooperativeKernel((const void*)csr_prep_kernel, dim3(CSR_GRID), dim3(256),
                               args, 0, stream);
  }

  // ---- layer 1: 129 -> 256 (H=2, C=128), Kpad=160 ----
  gemm_dual<2><<<dim3((N+127)/128, 2), 256, 0, stream>>>(Xbf, WT1, xl1bf, xr1bf, N, 160, 256);
  fused_gat_wave2<<<(N+3)/4, 256, 0, stream>>>(row_off, csr_src, xl1bf, xr1bf, a1, b1, h1bf, N);

  // ---- layer 2: 256 -> 128 (H=1, C=128), Kpad=256; fuses layer-3 projection ----
  unsigned short* xl2bf = (unsigned short*)A;                   // A lower (xl1bf dead)
  unsigned short* xr2bf = (unsigned short*)B;                   // B lower (xr1bf dead)
  gemm_dual<2><<<dim3((N+127)/128, 1), 256, 0, stream>>>(h1bf, WT2, xl2bf, xr2bf, N, 256, 128);
  fused_gat_wave1<<<(N+3)/4, 256, 0, stream>>>(row_off, csr_src, xl2bf, xr2bf, a2, b2,
                                               W3l, W3r, xl3, xr3, N);

  // ---- layer 3 aggregation + output (per train index; h3 never materialized) ----
  aggr3out_wave<<<(T+3)/4, 256, 0, stream>>>(row_off, csr_src, xl3, xr3, a3, b3,
                                             y, tidx, (float*)d_out, T);
}

// Round 16
// 390.545 us; speedup vs baseline: 2.5067x; 2.5067x over previous
//
#include <hip/hip_runtime.h>
#include <cmath>

typedef __attribute__((ext_vector_type(2))) float v2f;

__device__ __forceinline__ float lo16(unsigned u){ union{unsigned x; float f;} c; c.x = u << 16; return c.f; }
__device__ __forceinline__ float hi16(unsigned u){ union{unsigned x; float f;} c; c.x = u & 0xffff0000u; return c.f; }
__device__ __forceinline__ v2f pkmax(v2f a, v2f b){ v2f r; r.x = fmaxf(a.x,b.x); r.y = fmaxf(a.y,b.y); return r; }
__device__ __forceinline__ v2f mkv2(unsigned u){ v2f r; r.x = lo16(u); r.y = hi16(u); return r; }
__device__ __forceinline__ unsigned short f2bf(float f){
  union { float f; unsigned u; } c; c.f = f;
  unsigned u = c.u + 0x7FFFu + ((c.u >> 16) & 1u);
  return (unsigned short)(u >> 16);
}
__device__ __forceinline__ unsigned pack2bf(float a, float b){
  return (unsigned)f2bf(a) | ((unsigned)f2bf(b) << 16);
}
// safe merge factor: exp(m-M), giving 1 when m==M (handles -inf==-inf)
__device__ __forceinline__ float mergef(float m, float M){ return (m == M) ? 1.f : __expf(m - M); }

#define LOG2E 1.4426950408889634f

typedef __attribute__((ext_vector_type(8))) short bfrag;   // 8 bf16 = 4 VGPR
typedef __attribute__((ext_vector_type(4))) float ffrag;   // 4 f32 acc

// ---------------- CSR build ----------------

__global__ void deg_kernel(const int* __restrict__ dst, int* __restrict__ degi, int E){
  int e = blockIdx.x*256 + threadIdx.x;
  if (e < E) atomicAdd(&degi[dst[e]], 1);
}

__global__ void scan_p1(const int* __restrict__ degi, int* __restrict__ bsum, int N){
  __shared__ int red[256];
  int t = threadIdx.x;
  int i = blockIdx.x*256 + t;
  red[t] = (i < N) ? degi[i] : 0;
  __syncthreads();
  for (int off = 128; off > 0; off >>= 1){
    if (t < off) red[t] += red[t + off];
    __syncthreads();
  }
  if (t == 0) bsum[blockIdx.x] = red[0];
}

__global__ void scan_p2(const int* __restrict__ bsum, int* __restrict__ boff,
                        int* __restrict__ row_off, int NB, int N){
  __shared__ int s[256];
  int t = threadIdx.x;
  int v = (t < NB) ? bsum[t] : 0;
  s[t] = v;
  __syncthreads();
  for (int off = 1; off < 256; off <<= 1){
    int q = (t >= off) ? s[t - off] : 0;
    __syncthreads();
    s[t] += q;
    __syncthreads();
  }
  if (t < NB) boff[t] = s[t] - v;
  if (t == NB-1) row_off[N] = s[t];
}

// writes row_off AND cur (scatter's running cursor starts at row_off)
__global__ void scan_p3(const int* __restrict__ degi, const int* __restrict__ boff,
                        int* __restrict__ row_off, int* __restrict__ cur, int N){
  __shared__ int s[256];
  int t = threadIdx.x;
  int i = blockIdx.x*256 + t;
  int v = (i < N) ? degi[i] : 0;
  s[t] = v;
  __syncthreads();
  for (int off = 1; off < 256; off <<= 1){
    int q = (t >= off) ? s[t - off] : 0;
    __syncthreads();
    s[t] += q;
    __syncthreads();
  }
  if (i < N){
    int ro = boff[blockIdx.x] + s[t] - v;
    row_off[i] = ro;
    cur[i] = ro;
  }
}

__global__ void scatter_kernel(const int* __restrict__ src, const int* __restrict__ dst,
                               int* __restrict__ cur, int* __restrict__ csr_src, int E){
  int e = blockIdx.x*256 + threadIdx.x;
  if (e < E){
    int pos = atomicAdd(&cur[dst[e]], 1);
    csr_src[pos] = src[e];
  }
}

// ---------------- fused precision-prep: Xbf(pad) + WT1 + WT2 ----------------

__global__ void prep_all(const float* __restrict__ x,
                         const float* __restrict__ W1l, const float* __restrict__ W1r,
                         const float* __restrict__ W2l, const float* __restrict__ W2r,
                         unsigned short* __restrict__ Xbf,
                         unsigned short* __restrict__ WT1,
                         unsigned short* __restrict__ WT2, int N){
  int idx = blockIdx.x*256 + threadIdx.x;
  int n1 = N*160;              // x [N,129] -> Xbf [N,160]
  int n2 = 2*256*160;          // WT1 [512,160] from W1l/W1r [129,256]
  int n3 = 2*128*256;          // WT2 [256,256] from W2l/W2r [256,128]
  if (idx < n1){
    int n = idx / 160, k = idx - n*160;
    Xbf[idx] = (k < 129) ? f2bf(x[(size_t)n*129 + k]) : (unsigned short)0;
  } else if (idx < n1 + n2){
    int j = idx - n1;
    int c = j / 160, k = j - c*160;
    float v = 0.f;
    if (k < 129) v = (c < 256) ? W1l[(size_t)k*256 + c] : W1r[(size_t)k*256 + (c - 256)];
    WT1[j] = f2bf(v);
  } else if (idx < n1 + n2 + n3){
    int j = idx - n1 - n2;
    int c = j >> 8, k = j & 255;
    float v = (c < 128) ? W2l[(size_t)k*128 + c] : W2r[(size_t)k*128 + (c - 128)];
    WT2[j] = f2bf(v);
  }
}

// ---------------- dual MFMA bf16 GEMM, CB col-tiles of 128 per block ----------------

template<int CB>
__global__ __launch_bounds__(256) void gemm_dual(const unsigned short* __restrict__ Xbf,
                                                 const unsigned short* __restrict__ WT,
                                                 unsigned short* __restrict__ outL,
                                                 unsigned short* __restrict__ outR,
                                                 int N, int Kpad, int Mhalf){
  __shared__ __attribute__((aligned(16))) unsigned short Xs[128*40];
  __shared__ __attribute__((aligned(16))) unsigned short Ws[CB*128*40];
  int t = threadIdx.x;
  int n0 = blockIdx.x*128, c0 = blockIdx.y*(CB*128);
  int wv = t >> 6, lane = t & 63;
  int wr = wv >> 1, wc = wv & 1;
  int m16 = lane & 15, quad = lane >> 4;

  ffrag acc[CB][4][4];
  #pragma unroll
  for (int cb = 0; cb < CB; cb++)
    #pragma unroll
    for (int i = 0; i < 4; i++)
      #pragma unroll
      for (int j = 0; j < 4; j++) acc[cb][i][j] = (ffrag){0.f,0.f,0.f,0.f};

  for (int k0 = 0; k0 < Kpad; k0 += 32){
    uint4 zero = {0,0,0,0};
    #pragma unroll
    for (int it = 0; it < 2; it++){
      int idx = t + it*256;
      int r = idx >> 2, g = idx & 3;
      int n = n0 + r;
      uint4 v = (n < N) ? *(const uint4*)&Xbf[(size_t)n*Kpad + k0 + g*8] : zero;
      *(uint4*)&Xs[r*40 + g*8] = v;
    }
    #pragma unroll
    for (int it = 0; it < 2*CB; it++){
      int idx = t + it*256;
      int c = idx >> 2, g = idx & 3;
      uint4 v = *(const uint4*)&WT[(size_t)(c0 + c)*Kpad + k0 + g*8];
      *(uint4*)&Ws[c*40 + g*8] = v;
    }
    __syncthreads();
    bfrag a[4];
    #pragma unroll
    for (int i = 0; i < 4; i++)
      a[i] = *(const bfrag*)&Xs[(wr*64 + i*16 + m16)*40 + quad*8];
    #pragma unroll
    for (int cb = 0; cb < CB; cb++){
      bfrag b[4];
      #pragma unroll
      for (int j = 0; j < 4; j++)
        b[j] = *(const bfrag*)&Ws[(cb*128 + wc*64 + j*16 + m16)*40 + quad*8];
      #pragma unroll
      for (int i = 0; i < 4; i++)
        #pragma unroll
        for (int j = 0; j < 4; j++)
          acc[cb][i][j] = __builtin_amdgcn_mfma_f32_16x16x32_bf16(a[i], b[j], acc[cb][i][j], 0, 0, 0);
    }
    __syncthreads();
  }

  #pragma unroll
  for (int cb = 0; cb < CB; cb++){
    int gc0 = c0 + cb*128;
    bool isL = (gc0 < Mhalf);
    unsigned short* outp = isL ? outL : outR;
    int ccol0 = isL ? gc0 : (gc0 - Mhalf);
    #pragma unroll
    for (int i = 0; i < 4; i++){
      #pragma unroll
      for (int reg = 0; reg < 4; reg++){
        int rr = n0 + wr*64 + i*16 + quad*4 + reg;
        if (rr >= N) continue;
        #pragma unroll
        for (int j = 0; j < 4; j++){
          int cc = ccol0 + wc*64 + j*16 + m16;
          outp[(size_t)rr*Mhalf + cc] = f2bf(acc[cb][i][j][reg]);
        }
      }
    }
  }
}

// ---------------- fused GATv2 edge phase (packed-f32 channel math) ----------------
// H=2, CH=256: wave per node, 2 edge slots x 32 lanes (16/head), 8 ch/lane. bf16 in/out.

__global__ __launch_bounds__(256) void fused_gat_wave2(
    const int* __restrict__ row_off, const int* __restrict__ csr_src,
    const unsigned short* __restrict__ xlbf, const unsigned short* __restrict__ xrbf,
    const float* __restrict__ att, const float* __restrict__ bias,
    unsigned short* __restrict__ outbf, int N)
{
  int n = blockIdx.x*4 + (threadIdx.x >> 6);
  if (n >= N) return;
  int lane = threadIdx.x & 63;
  int slot = lane >> 5;
  int sub  = lane & 31;
  int ch0  = sub*8;
  int r0 = row_off[n], r1 = row_off[n+1];
  int deg = r1 - r0;

  uint4 xru = *(const uint4*)&xrbf[(size_t)n*256 + ch0];
  v2f q01 = mkv2(xru.x), q23 = mkv2(xru.y), q45 = mkv2(xru.z), q67 = mkv2(xru.w);
  const v2f* atp = (const v2f*)(att + ch0);
  v2f at01 = atp[0], at23 = atp[1], at45 = atp[2], at67 = atp[3];

  float m = -INFINITY, l = 0.f;
  v2f A01 = {0.f,0.f}, A23 = {0.f,0.f}, A45 = {0.f,0.f}, A67 = {0.f,0.f};

  if (deg > 0){
    int p = r0 + slot;
    int pc = min(p, r1-1);
    uint4 cur = *(const uint4*)&xlbf[(size_t)csr_src[pc]*256 + ch0];
    for (; p < r1; p += 2){
      int pn = min(p+2, r1-1);
      uint4 nxt = *(const uint4*)&xlbf[(size_t)csr_src[pn]*256 + ch0];
      v2f x01 = mkv2(cur.x), x23 = mkv2(cur.y), x45 = mkv2(cur.z), x67 = mkv2(cur.w);
      v2f t01 = x01 + q01, t23 = x23 + q23, t45 = x45 + q45, t67 = x67 + q67;
      v2f dv = pkmax(t01, t01*0.2f)*at01;
      dv += pkmax(t23, t23*0.2f)*at23;
      dv += pkmax(t45, t45*0.2f)*at45;
      dv += pkmax(t67, t67*0.2f)*at67;
      float dot = dv.x + dv.y;
      dot += __shfl_xor(dot, 8);
      dot += __shfl_xor(dot, 4);
      dot += __shfl_xor(dot, 2);
      dot += __shfl_xor(dot, 1);   // per-16-lane (head) logit
      if (dot <= m){
        float w_ = __expf(dot - m);
        l += w_;
        A01 += x01*w_; A23 += x23*w_; A45 += x45*w_; A67 += x67*w_;
      } else {
        float sc = __expf(m - dot);   // 0 on first edge (m=-inf)
        l = l*sc + 1.f;
        A01 = A01*sc + x01; A23 = A23*sc + x23; A45 = A45*sc + x45; A67 = A67*sc + x67;
        m = dot;
      }
      cur = nxt;
    }
  }

  const float4* bvp = (const float4*)(bias + ch0);
  float4 res0 = bvp[0], res1 = bvp[1];
  if (deg > 0){
    float m2 = __shfl_xor(m, 32);
    float l2 = __shfl_xor(l, 32);
    float M  = fmaxf(m, m2);
    float fa = mergef(m, M), fb = mergef(m2, M);
    float L  = l*fa + l2*fb;
    v2f q;
    q.x = __shfl_xor(A01.x,32); q.y = __shfl_xor(A01.y,32); A01 = A01*fa + q*fb;
    q.x = __shfl_xor(A23.x,32); q.y = __shfl_xor(A23.y,32); A23 = A23*fa + q*fb;
    q.x = __shfl_xor(A45.x,32); q.y = __shfl_xor(A45.y,32); A45 = A45*fa + q*fb;
    q.x = __shfl_xor(A67.x,32); q.y = __shfl_xor(A67.y,32); A67 = A67*fa + q*fb;
    float inv = 1.f / (L * (float)deg);
    res0.x += A01.x*inv; res0.y += A01.y*inv; res0.z += A23.x*inv; res0.w += A23.y*inv;
    res1.x += A45.x*inv; res1.y += A45.y*inv; res1.z += A67.x*inv; res1.w += A67.y*inv;
  }
  if (slot == 0){
    uint4 u;
    u.x = pack2bf(res0.x, res0.y);
    u.y = pack2bf(res0.z, res0.w);
    u.z = pack2bf(res1.x, res1.y);
    u.w = pack2bf(res1.z, res1.w);
    *(uint4*)&outbf[(size_t)n*256 + ch0] = u;
  }
}

// H=1, CH=128: wave per node, 4 edge slots x 16 lanes, 8 ch/lane.
// Epilogue fuses layer-3 projection (h2 never stored).

__global__ __launch_bounds__(256) void fused_gat_wave1(
    const int* __restrict__ row_off, const int* __restrict__ csr_src,
    const unsigned short* __restrict__ xlbf, const unsigned short* __restrict__ xrbf,
    const float* __restrict__ att, const float* __restrict__ bias,
    const float* __restrict__ W3l, const float* __restrict__ W3r,
    float* __restrict__ xl3, float* __restrict__ xr3, int N)
{
  int n = blockIdx.x*4 + (threadIdx.x >> 6);
  if (n >= N) return;
  int lane = threadIdx.x & 63;
  int slot = lane >> 4;
  int sub  = lane & 15;
  int ch0  = sub*8;
  int r0 = row_off[n], r1 = row_off[n+1];
  int deg = r1 - r0;

  uint4 xru = *(const uint4*)&xrbf[(size_t)n*128 + ch0];
  v2f q01 = mkv2(xru.x), q23 = mkv2(xru.y), q45 = mkv2(xru.z), q67 = mkv2(xru.w);
  const v2f* atp = (const v2f*)(att + ch0);
  v2f at01 = atp[0], at23 = atp[1], at45 = atp[2], at67 = atp[3];

  float m = -INFINITY, l = 0.f;
  v2f A01 = {0.f,0.f}, A23 = {0.f,0.f}, A45 = {0.f,0.f}, A67 = {0.f,0.f};

  if (deg > 0){
    int p = r0 + slot;
    int pc = min(p, r1-1);
    uint4 cur = *(const uint4*)&xlbf[(size_t)csr_src[pc]*128 + ch0];
    for (; p < r1; p += 4){
      int pn = min(p+4, r1-1);
      uint4 nxt = *(const uint4*)&xlbf[(size_t)csr_src[pn]*128 + ch0];
      v2f x01 = mkv2(cur.x), x23 = mkv2(cur.y), x45 = mkv2(cur.z), x67 = mkv2(cur.w);
      v2f t01 = x01 + q01, t23 = x23 + q23, t45 = x45 + q45, t67 = x67 + q67;
      v2f dv = pkmax(t01, t01*0.2f)*at01;
      dv += pkmax(t23, t23*0.2f)*at23;
      dv += pkmax(t45, t45*0.2f)*at45;
      dv += pkmax(t67, t67*0.2f)*at67;
      float dot = dv.x + dv.y;
      dot += __shfl_xor(dot, 8);
      dot += __shfl_xor(dot, 4);
      dot += __shfl_xor(dot, 2);
      dot += __shfl_xor(dot, 1);   // per-16-lane logit
      if (dot <= m){
        float w_ = __expf(dot - m);
        l += w_;
        A01 += x01*w_; A23 += x23*w_; A45 += x45*w_; A67 += x67*w_;
      } else {
        float sc = __expf(m - dot);
        l = l*sc + 1.f;
        A01 = A01*sc + x01; A23 = A23*sc + x23; A45 = A45*sc + x45; A67 = A67*sc + x67;
        m = dot;
      }
      cur = nxt;
    }
  }

  if (deg > 0){
    #pragma unroll
    for (int stage = 0; stage < 2; stage++){
      int d = 16 << stage;
      float m2 = __shfl_xor(m, d);
      float l2 = __shfl_xor(l, d);
      float M  = fmaxf(m, m2);
      float fa = mergef(m, M), fb = mergef(m2, M);
      l = l*fa + l2*fb;
      v2f q;
      q.x = __shfl_xor(A01.x,d); q.y = __shfl_xor(A01.y,d); A01 = A01*fa + q*fb;
      q.x = __shfl_xor(A23.x,d); q.y = __shfl_xor(A23.y,d); A23 = A23*fa + q*fb;
      q.x = __shfl_xor(A45.x,d); q.y = __shfl_xor(A45.y,d); A45 = A45*fa + q*fb;
      q.x = __shfl_xor(A67.x,d); q.y = __shfl_xor(A67.y,d); A67 = A67*fa + q*fb;
      m = M;
    }
  }
  float inv = (deg > 0) ? 1.f/(l*(float)deg) : 0.f;
  const float4* bvp = (const float4*)(bias + ch0);
  float4 res0 = bvp[0], res1 = bvp[1];
  res0.x += A01.x*inv; res0.y += A01.y*inv; res0.z += A23.x*inv; res0.w += A23.y*inv;
  res1.x += A45.x*inv; res1.y += A45.y*inv; res1.z += A67.x*inv; res1.w += A67.y*inv;

  // layer-3 projection in-register: h2 row = res; dot with W3l/W3r
  float4 wla = *(const float4*)(W3l + ch0);
  float4 wlb = *(const float4*)(W3l + ch0 + 4);
  float4 wra = *(const float4*)(W3r + ch0);
  float4 wrb = *(const float4*)(W3r + ch0 + 4);
  float sl = res0.x*wla.x + res0.y*wla.y + res0.z*wla.z + res0.w*wla.w
           + res1.x*wlb.x + res1.y*wlb.y + res1.z*wlb.z + res1.w*wlb.w;
  float sr = res0.x*wra.x + res0.y*wra.y + res0.z*wra.z + res0.w*wra.w
           + res1.x*wrb.x + res1.y*wrb.y + res1.z*wrb.z + res1.w*wrb.w;
  sl += __shfl_xor(sl, 8); sl += __shfl_xor(sl, 4); sl += __shfl_xor(sl, 2); sl += __shfl_xor(sl, 1);
  sr += __shfl_xor(sr, 8); sr += __shfl_xor(sr, 4); sr += __shfl_xor(sr, 2); sr += __shfl_xor(sr, 1);
  if (lane == 0){ xl3[n] = sl; xr3[n] = sr; }
}

// ---------------- layer 3 aggregation + output, per train index (exp2 domain) ----------------

__global__ __launch_bounds__(256) void aggr3out_wave(
    const int* __restrict__ row_off, const int* __restrict__ csr_src,
    const float* __restrict__ xl3, const float* __restrict__ xr3,
    const float* __restrict__ a3, const float* __restrict__ b3,
    const float* __restrict__ y, const int* __restrict__ tidx,
    float* __restrict__ out, int T)
{
  int i = blockIdx.x*4 + (threadIdx.x >> 6);
  if (i >= T) return;
  int lane = threadIdx.x & 63;
  int n = tidx[i];
  int r0 = row_off[n], r1 = row_off[n+1];
  int deg = r1 - r0;
  float b = b3[0];
  float h;
  if (deg == 0){
    h = b;
  } else {
    float xrv = xr3[n];
    float aa = a3[0] * LOG2E;
    float m = -INFINITY, den = 0.f, s = 0.f;
    for (int base = r0; base < r1; base += 64){
      int p = base + lane;
      bool valid = p < r1;
      float xlv = valid ? xl3[csr_src[p]] : 0.f;
      float t = xlv + xrv;
      float v = fmaxf(t, 0.2f*t) * aa;
      if (!valid) v = -INFINITY;
      float bm = v;
      #pragma unroll
      for (int off = 32; off > 0; off >>= 1) bm = fmaxf(bm, __shfl_xor(bm, off));
      float nm = fmaxf(m, bm);
      float a = valid ? exp2f(v - nm) : 0.f;
      float bd = a, bs = a * xlv;
      #pragma unroll
      for (int off = 32; off > 0; off >>= 1){
        bd += __shfl_xor(bd, off);
        bs += __shfl_xor(bs, off);
      }
      float sc = exp2f(m - nm);
      den = den*sc + bd;
      s   = s*sc + bs;
      m = nm;
    }
    h = s/den/(float)deg + b;
  }
  if (lane == 0){
    out[i] = 1.f/(1.f + __expf(-h));
    out[T + i] = y[n];
  }
}

// ---------------- launch ----------------

extern "C" void kernel_launch(void* const* d_in, const int* in_sizes, int n_in,
                              void* d_out, int out_size, void* d_ws, size_t ws_size,
                              hipStream_t stream){
  const float* x    = (const float*)d_in[0];
  const int*   ei   = (const int*)d_in[1];
  const float* y    = (const float*)d_in[2];
  const int*   tidx = (const int*)d_in[3];
  const float* W1l  = (const float*)d_in[4];
  const float* W1r  = (const float*)d_in[5];
  const float* a1   = (const float*)d_in[6];
  const float* b1   = (const float*)d_in[7];
  const float* W2l  = (const float*)d_in[8];
  const float* W2r  = (const float*)d_in[9];
  const float* a2   = (const float*)d_in[10];
  const float* b2   = (const float*)d_in[11];
  const float* W3l  = (const float*)d_in[12];
  const float* W3r  = (const float*)d_in[13];
  const float* a3   = (const float*)d_in[14];
  const float* b3   = (const float*)d_in[15];

  int N = in_sizes[2];        // 50000 nodes
  int E = in_sizes[1] / 2;    // 800000 edges
  int T = in_sizes[3];        // 40000 train indices
  const int* src = ei;
  const int* dst = ei + E;
  int NB = (N + 255) / 256;

  char* w = (char*)d_ws;
  size_t off = 0;
  auto take = [&](size_t bytes) -> char* {
    char* p = w + off;
    off = (off + bytes + 255) & ~(size_t)255;
    return p;
  };
  int*   row_off = (int*)  take((size_t)(N+1)*4);
  int*   degi    = (int*)  take((size_t)N*4);
  int*   cur     = (int*)  take((size_t)N*4);
  int*   bsum    = (int*)  take((size_t)NB*4);
  int*   boff    = (int*)  take((size_t)NB*4);
  int*   csr_src = (int*)  take((size_t)E*4);
  unsigned short* WT1 = (unsigned short*)take((size_t)512*160*2);
  unsigned short* WT2 = (unsigned short*)take((size_t)256*256*2);
  float* A       = (float*)take((size_t)N*256*4);
  float* B       = (float*)take((size_t)N*256*4);

  // ---- CSR build ----
  hipMemsetAsync(degi, 0, (size_t)N*4, stream);
  deg_kernel<<<(E+255)/256, 256, 0, stream>>>(dst, degi, E);
  scan_p1<<<NB, 256, 0, stream>>>(degi, bsum, N);
  scan_p2<<<1, 256, 0, stream>>>(bsum, boff, row_off, NB, N);
  scan_p3<<<NB, 256, 0, stream>>>(degi, boff, row_off, cur, N);
  scatter_kernel<<<(E+255)/256, 256, 0, stream>>>(src, dst, cur, csr_src, E);

  // ---- buffer map (floats units) ----
  unsigned short* xl1bf = (unsigned short*)A;                   // A lower: N*256 bf16
  unsigned short* Xbf   = (unsigned short*)(A + (size_t)N*128); // A upper: N*160 bf16
  unsigned short* h1bf  = (unsigned short*)(A + (size_t)N*128); // A upper after gemm1 (Xbf dead)
  unsigned short* xr1bf = (unsigned short*)B;                   // B lower: N*256 bf16
  float* Bu   = B + (size_t)N*128;                              // B upper
  float* xl3  = Bu;
  float* xr3  = Bu + N;

  // ---- prep: Xbf (N x 160), WT1, WT2 ----
  int prep_total = N*160 + 2*256*160 + 2*128*256;
  prep_all<<<(prep_total+255)/256, 256, 0, stream>>>(x, W1l, W1r, W2l, W2r, Xbf, WT1, WT2, N);

  // ---- layer 1: 129 -> 256 (H=2, C=128), Kpad=160 ----
  gemm_dual<2><<<dim3((N+127)/128, 2), 256, 0, stream>>>(Xbf, WT1, xl1bf, xr1bf, N, 160, 256);
  fused_gat_wave2<<<(N+3)/4, 256, 0, stream>>>(row_off, csr_src, xl1bf, xr1bf, a1, b1, h1bf, N);

  // ---- layer 2: 256 -> 128 (H=1, C=128), Kpad=256; fuses layer-3 projection ----
  unsigned short* xl2bf = (unsigned short*)A;                   // A lower (xl1bf dead)
  unsigned short* xr2bf = (unsigned short*)B;                   // B lower (xr1bf dead)
  gemm_dual<2><<<dim3((N+127)/128, 1), 256, 0, stream>>>(h1bf, WT2, xl2bf, xr2bf, N, 256, 128);
  fused_gat_wave1<<<(N+3)/4, 256, 0, stream>>>(row_off, csr_src, xl2bf, xr2bf, a2, b2,
                                               W3l, W3r, xl3, xr3, N);

  // ---- layer 3 aggregation + output (per train index; h3 never materialized) ----
  aggr3out_wave<<<(T+3)/4, 256, 0, stream>>>(row_off, csr_src, xl3, xr3, a3, b3,
                                             y, tidx, (float*)d_out, T);
}